// Round 2
// baseline (766.085 us; speedup 1.0000x reference)
//
#include <hip/hip_runtime.h>
#include <hip/hip_bf16.h>

// ---------------------------------------------------------------------------
// HierarchicalEnvironmentDetector — fp32 baseline (r2: fix Bs half-tile bug)
//   obs[256,12,84,84] -> conv8x8s4(32) -> conv4x4s2(64) -> conv3x3s1(64)
//   -> flatten 3136 -> proj 1024 (relu) -> {cat logits 16 + softmax,
//   16 expert heads 1024->512(relu)->64(sigmoid), weighted scatter into 512}
// Outputs (flat f32): logits[256*16] | expert_probs[256*512] | hidden[256*1024]
// ---------------------------------------------------------------------------

#define B_    256
#define CIN   12
#define HH    84
#define WW    84
#define HID   1024
#define NC    16
#define NE    512
#define EPC   64
#define FLAT  3136

// ============================ conv1: 12->32, 8x8, s4, relu =================
// grid (oyp=10, b=256), block 320 = (ocp 16) x (ox 20). Each thread: 2 oc x 2 oy.
__global__ __launch_bounds__(320) void conv1_kernel(
        const float* __restrict__ obs, const float* __restrict__ k1,
        const float* __restrict__ cb1, float* __restrict__ x1) {
    __shared__ float slab[CIN][12][WW];       // 48384 B: rows 8*oyp .. 8*oyp+11
    const int oyp = blockIdx.x;               // 0..9 -> oy = 2*oyp, 2*oyp+1
    const int b   = blockIdx.y;
    const int tid = threadIdx.x;
    const int base_row = 8 * oyp;             // <= 72, +11 = 83 < 84 OK

    const float* src = obs + (size_t)b * CIN * HH * WW;
    float4* s4 = (float4*)&slab[0][0][0];
    // stage: per ic a contiguous window of 12 rows (1008 floats = 252 float4)
    for (int l = tid; l < CIN * 252; l += 320) {
        int ic = l / 252, off = l % 252;
        s4[ic * 252 + off] =
            *(const float4*)(src + (size_t)ic * HH * WW + base_row * WW + off * 4);
    }
    __syncthreads();

    const int ocp = tid / 20;                 // 0..15
    const int ox  = tid % 20;
    const int oc0 = ocp * 2;
    float acc00 = cb1[oc0],   acc01 = cb1[oc0 + 1];   // oy0
    float acc10 = cb1[oc0],   acc11 = cb1[oc0 + 1];   // oy1

    for (int ic = 0; ic < CIN; ++ic) {
        float wv[5][16];                      // rolling 5-slot window, slot=r%5
        #pragma unroll
        for (int r = 0; r < 12; ++r) {
            const float4* p4 = (const float4*)&slab[ic][r][4 * ox];
            float4 t0 = p4[0], t1 = p4[1];
            float uv[8] = {t0.x, t0.y, t0.z, t0.w, t1.x, t1.y, t1.z, t1.w};
            if (r < 8) {                      // load weights for ky=r, use for oy0
                const int s = r % 5;
                const float* wp = k1 + oc0 * 768 + ic * 64 + r * 8;
                float4 a0 = *(const float4*)(wp);
                float4 a1 = *(const float4*)(wp + 4);
                float4 b0 = *(const float4*)(wp + 768);
                float4 b1 = *(const float4*)(wp + 772);
                wv[s][0]=a0.x; wv[s][1]=a0.y; wv[s][2]=a0.z; wv[s][3]=a0.w;
                wv[s][4]=a1.x; wv[s][5]=a1.y; wv[s][6]=a1.z; wv[s][7]=a1.w;
                wv[s][8]=b0.x; wv[s][9]=b0.y; wv[s][10]=b0.z; wv[s][11]=b0.w;
                wv[s][12]=b1.x; wv[s][13]=b1.y; wv[s][14]=b1.z; wv[s][15]=b1.w;
                #pragma unroll
                for (int j = 0; j < 8; ++j) {
                    acc00 += uv[j] * wv[s][j];
                    acc01 += uv[j] * wv[s][8 + j];
                }
            }
            if (r >= 4) {                     // ky = r-4, loaded 4 iters ago
                const int s = (r - 4) % 5;
                #pragma unroll
                for (int j = 0; j < 8; ++j) {
                    acc10 += uv[j] * wv[s][j];
                    acc11 += uv[j] * wv[s][8 + j];
                }
            }
        }
    }
    const int oy0 = 2 * oyp;
    float* dst = x1 + (size_t)(b * 32 + oc0) * 400;   // [b][oc][20][20]
    dst[oy0 * 20 + ox]             = fmaxf(acc00, 0.f);
    dst[(oy0 + 1) * 20 + ox]       = fmaxf(acc10, 0.f);
    dst[400 + oy0 * 20 + ox]       = fmaxf(acc01, 0.f);
    dst[400 + (oy0 + 1) * 20 + ox] = fmaxf(acc11, 0.f);
}

// ============================ conv2: 32->64, 4x4, s2, relu =================
// grid b=256, block 288 = (ocp 32) x (oy 9). Thread: 2 oc x 9 ox.
__global__ __launch_bounds__(288) void conv2_kernel(
        const float* __restrict__ x1, const float* __restrict__ k2,
        const float* __restrict__ cb2, float* __restrict__ x2) {
    __shared__ float slab[32][20][20];        // 51200 B, whole image
    const int b = blockIdx.x, tid = threadIdx.x;
    const float* src = x1 + (size_t)b * 32 * 400;
    float4* s4 = (float4*)&slab[0][0][0];
    const float4* g4 = (const float4*)src;
    for (int l = tid; l < 3200; l += 288) s4[l] = g4[l];
    __syncthreads();

    const int ocp = tid / 9, oy = tid % 9;    // ocp 0..31
    const int oc0 = 2 * ocp;
    float acc[2][9];
    #pragma unroll
    for (int o = 0; o < 2; ++o) {
        float bv = cb2[oc0 + o];
        #pragma unroll
        for (int i = 0; i < 9; ++i) acc[o][i] = bv;
    }
    for (int ic = 0; ic < 32; ++ic) {
        float wvv[2][16];                     // k2[(oc)*512 + ic*16 + ky*4 + kx]
        const float* wp = k2 + oc0 * 512 + ic * 16;
        #pragma unroll
        for (int o = 0; o < 2; ++o) {
            #pragma unroll
            for (int ky = 0; ky < 4; ++ky) {
                float4 t = *(const float4*)(wp + o * 512 + 4 * ky);
                wvv[o][4*ky] = t.x; wvv[o][4*ky+1] = t.y;
                wvv[o][4*ky+2] = t.z; wvv[o][4*ky+3] = t.w;
            }
        }
        #pragma unroll
        for (int ky = 0; ky < 4; ++ky) {
            const int row = 2 * oy + ky;      // 0..19
            float rf[20];
            const float4* rp = (const float4*)&slab[ic][row][0];
            #pragma unroll
            for (int q = 0; q < 5; ++q) {
                float4 t = rp[q];
                rf[4*q] = t.x; rf[4*q+1] = t.y; rf[4*q+2] = t.z; rf[4*q+3] = t.w;
            }
            #pragma unroll
            for (int ox = 0; ox < 9; ++ox) {
                #pragma unroll
                for (int kx = 0; kx < 4; ++kx) {
                    float v = rf[2 * ox + kx];
                    acc[0][ox] += v * wvv[0][4 * ky + kx];
                    acc[1][ox] += v * wvv[1][4 * ky + kx];
                }
            }
        }
    }
    #pragma unroll
    for (int o = 0; o < 2; ++o) {
        float* dst = x2 + ((size_t)(b * 64 + oc0 + o) * 9 + oy) * 9;
        #pragma unroll
        for (int ox = 0; ox < 9; ++ox) dst[ox] = fmaxf(acc[o][ox], 0.f);
    }
}

// ============================ conv3: 64->64, 3x3, s1, relu =================
// grid b=256, block 224 = (ocp 32) x (oy 7). Thread: 2 oc x 7 ox. Writes feats.
__global__ __launch_bounds__(224) void conv3_kernel(
        const float* __restrict__ x2, const float* __restrict__ k3,
        const float* __restrict__ cb3, float* __restrict__ feats) {
    __shared__ float slab[64][9][12];         // rows padded 9->12 for float4
    const int b = blockIdx.x, tid = threadIdx.x;
    for (int l = tid; l < 64 * 9 * 12; l += 224) {
        int ic = l / 108, rest = l % 108, r = rest / 12, x = rest % 12;
        slab[ic][r][x] = (x < 9) ? x2[((size_t)(b * 64 + ic) * 9 + r) * 9 + x] : 0.f;
    }
    __syncthreads();

    const int ocp = tid / 7, oy = tid % 7;    // ocp 0..31
    const int oc0 = 2 * ocp;
    float acc[2][7];
    #pragma unroll
    for (int o = 0; o < 2; ++o) {
        float bv = cb3[oc0 + o];
        #pragma unroll
        for (int i = 0; i < 7; ++i) acc[o][i] = bv;
    }
    for (int ic = 0; ic < 64; ++ic) {
        float wv2[2][9];                      // k3[(oc)*576 + ic*9 + 3ky+kx]
        const float* wp = k3 + oc0 * 576 + ic * 9;
        #pragma unroll
        for (int j = 0; j < 9; ++j) { wv2[0][j] = wp[j]; wv2[1][j] = wp[576 + j]; }
        #pragma unroll
        for (int ky = 0; ky < 3; ++ky) {
            const int row = oy + ky;          // 0..8
            float rf[12];
            const float4* rp = (const float4*)&slab[ic][row][0];
            #pragma unroll
            for (int q = 0; q < 3; ++q) {
                float4 t = rp[q];
                rf[4*q] = t.x; rf[4*q+1] = t.y; rf[4*q+2] = t.z; rf[4*q+3] = t.w;
            }
            #pragma unroll
            for (int ox = 0; ox < 7; ++ox) {
                #pragma unroll
                for (int kx = 0; kx < 3; ++kx) {
                    float v = rf[ox + kx];
                    acc[0][ox] += v * wv2[0][3 * ky + kx];
                    acc[1][ox] += v * wv2[1][3 * ky + kx];
                }
            }
        }
    }
    // feats[b][oc*49 + oy*7 + ox]  (== NCHW flatten)
    #pragma unroll
    for (int o = 0; o < 2; ++o) {
        float* dst = feats + (size_t)b * FLAT + (oc0 + o) * 49 + oy * 7;
        #pragma unroll
        for (int ox = 0; ox < 7; ++ox) dst[ox] = fmaxf(acc[o][ox], 0.f);
    }
}

// ===================== proj GEMM (split-K=16, atomic accumulate) ===========
// 64x128 tile, 256 thr, thread = 8m x 4n. grid (nb=8, mb=4, z=16)
__global__ __launch_bounds__(256) void proj_gemm_kernel(
        const float* __restrict__ A, const float* __restrict__ Bm,
        float* __restrict__ accum) {
    __shared__ float As[16][64];
    __shared__ float Bs[16][128];
    const int tid = threadIdx.x;
    const int n0 = blockIdx.x * 128, m0 = blockIdx.y * 64;
    const int kbeg = blockIdx.z * 196, kend = kbeg + 196;   // 16*196 = 3136
    const int tx = tid & 31, ty = tid >> 5;
    const int ar = tid >> 2, akq = tid & 3;   // A stage: row ar, k-chunk akq
    const int bk = tid >> 4, bn = tid & 15;   // B stage: k-row bk, col 4*bn & 64+4*bn
    float acc[8][4] = {{0.f}};

    for (int kt = kbeg; kt < kend; kt += 16) {
        {
            int k = kt + 4 * akq;
            float4 v = make_float4(0.f, 0.f, 0.f, 0.f);
            if (k < kend) v = *(const float4*)&A[(size_t)(m0 + ar) * FLAT + k];
            As[4*akq+0][ar] = v.x; As[4*akq+1][ar] = v.y;
            As[4*akq+2][ar] = v.z; As[4*akq+3][ar] = v.w;
        }
        {
            int k = kt + bk;
            float4 v0 = make_float4(0.f, 0.f, 0.f, 0.f);
            float4 v1 = make_float4(0.f, 0.f, 0.f, 0.f);
            if (k < kend) {
                v0 = *(const float4*)&Bm[(size_t)k * HID + n0 + 4 * bn];
                v1 = *(const float4*)&Bm[(size_t)k * HID + n0 + 64 + 4 * bn];
            }
            *(float4*)&Bs[bk][4 * bn]      = v0;
            *(float4*)&Bs[bk][64 + 4 * bn] = v1;
        }
        __syncthreads();
        #pragma unroll
        for (int kk = 0; kk < 16; ++kk) {
            float4 a0 = *(const float4*)&As[kk][8 * ty];
            float4 a1 = *(const float4*)&As[kk][8 * ty + 4];
            float4 bv = *(const float4*)&Bs[kk][4 * tx];
            float av[8] = {a0.x,a0.y,a0.z,a0.w,a1.x,a1.y,a1.z,a1.w};
            float bb[4] = {bv.x,bv.y,bv.z,bv.w};
            #pragma unroll
            for (int i = 0; i < 8; ++i)
                #pragma unroll
                for (int j = 0; j < 4; ++j) acc[i][j] += av[i] * bb[j];
        }
        __syncthreads();
    }
    #pragma unroll
    for (int i = 0; i < 8; ++i)
        #pragma unroll
        for (int j = 0; j < 4; ++j)
            atomicAdd(&accum[(size_t)(m0 + 8*ty + i) * HID + n0 + 4*tx + j], acc[i][j]);
}

// proj epilogue: hidden = relu(accum + bproj) -> d_out hidden region
__global__ __launch_bounds__(256) void proj_epi_kernel(
        const float* __restrict__ accum, const float* __restrict__ bproj,
        float* __restrict__ hidden) {
    const int i = blockIdx.x * 256 + threadIdx.x;    // 65536 float4
    float4 v = *(const float4*)&accum[4 * i];
    float4 bb = *(const float4*)&bproj[(4 * i) & (HID - 1)];
    float4 r;
    r.x = fmaxf(v.x + bb.x, 0.f); r.y = fmaxf(v.y + bb.y, 0.f);
    r.z = fmaxf(v.z + bb.z, 0.f); r.w = fmaxf(v.w + bb.w, 0.f);
    *(float4*)&hidden[4 * i] = r;
}

// ============ category head + softmax: logits & probs ======================
__global__ __launch_bounds__(256) void cat_softmax_kernel(
        const float* __restrict__ hidden, const float* __restrict__ Wcat,
        const float* __restrict__ bcat, float* __restrict__ logits,
        float* __restrict__ probs) {
    __shared__ float red[256];
    __shared__ float lvals[16];
    const int b = blockIdx.x, tid = threadIdx.x;
    const int cc = tid & 15, kq = tid >> 4;
    const float* hrow = hidden + (size_t)b * HID;
    float p = 0.f;
    for (int t = 0; t < 64; ++t) {
        int k = kq * 64 + t;
        p += hrow[k] * Wcat[k * NC + cc];
    }
    red[tid] = p;
    __syncthreads();
    if (tid < 16) {
        float s = bcat[tid];
        #pragma unroll
        for (int q = 0; q < 16; ++q) s += red[q * 16 + tid];
        logits[b * NC + tid] = s;
        lvals[tid] = s;
    }
    __syncthreads();
    if (tid < 16) {
        float m = lvals[0];
        #pragma unroll
        for (int q = 1; q < 16; ++q) m = fmaxf(m, lvals[q]);
        float sum = 0.f;
        #pragma unroll
        for (int q = 0; q < 16; ++q) sum += expf(lvals[q] - m);
        probs[b * NC + tid] = expf(lvals[tid] - m) / sum;
    }
}

// ===================== expert GEMM1: h1 = relu(hidden @ W1[c] + b1[c]) =====
// 64x128 tile, thread 8m x 4n. grid (nb=4, mb=4, c=16). h1 layout [c][b][512]
__global__ __launch_bounds__(256) void expert1_gemm_kernel(
        const float* __restrict__ A, const float* __restrict__ W1,
        const float* __restrict__ b1, float* __restrict__ h1) {
    __shared__ float As[16][64];
    __shared__ float Bs[16][128];
    const int tid = threadIdx.x;
    const int n0 = blockIdx.x * 128, m0 = blockIdx.y * 64;
    const int c = blockIdx.z;
    const float* Bm = W1 + (size_t)c * HID * (HID / 2);
    const int tx = tid & 31, ty = tid >> 5;
    const int ar = tid >> 2, akq = tid & 3;
    const int bk = tid >> 4, bn = tid & 15;
    float acc[8][4] = {{0.f}};

    for (int kt = 0; kt < HID; kt += 16) {
        {
            float4 v = *(const float4*)&A[(size_t)(m0 + ar) * HID + kt + 4 * akq];
            As[4*akq+0][ar] = v.x; As[4*akq+1][ar] = v.y;
            As[4*akq+2][ar] = v.z; As[4*akq+3][ar] = v.w;
        }
        {
            const float* bp = Bm + (size_t)(kt + bk) * (HID / 2) + n0;
            *(float4*)&Bs[bk][4 * bn]      = *(const float4*)&bp[4 * bn];
            *(float4*)&Bs[bk][64 + 4 * bn] = *(const float4*)&bp[64 + 4 * bn];
        }
        __syncthreads();
        #pragma unroll
        for (int kk = 0; kk < 16; ++kk) {
            float4 a0 = *(const float4*)&As[kk][8 * ty];
            float4 a1 = *(const float4*)&As[kk][8 * ty + 4];
            float4 bv = *(const float4*)&Bs[kk][4 * tx];
            float av[8] = {a0.x,a0.y,a0.z,a0.w,a1.x,a1.y,a1.z,a1.w};
            float bb[4] = {bv.x,bv.y,bv.z,bv.w};
            #pragma unroll
            for (int i = 0; i < 8; ++i)
                #pragma unroll
                for (int j = 0; j < 4; ++j) acc[i][j] += av[i] * bb[j];
        }
        __syncthreads();
    }
    #pragma unroll
    for (int i = 0; i < 8; ++i) {
        float4 o;
        float b0 = b1[c * (HID/2) + n0 + 4*tx + 0];
        float b1v = b1[c * (HID/2) + n0 + 4*tx + 1];
        float b2v = b1[c * (HID/2) + n0 + 4*tx + 2];
        float b3v = b1[c * (HID/2) + n0 + 4*tx + 3];
        o.x = fmaxf(acc[i][0] + b0, 0.f);
        o.y = fmaxf(acc[i][1] + b1v, 0.f);
        o.z = fmaxf(acc[i][2] + b2v, 0.f);
        o.w = fmaxf(acc[i][3] + b3v, 0.f);
        *(float4*)&h1[((size_t)c * B_ + m0 + 8*ty + i) * (HID/2) + n0 + 4*tx] = o;
    }
}

// ======= expert head2 fused: sigmoid(h1@W2+b2) * probs -> scatter-add ======
// grid (b=256, cq=8), block 64: c = 2*cq + tid/32, e = 2*(tid%32) + {0,1}
__global__ __launch_bounds__(64) void expert2_fused_kernel(
        const float* __restrict__ h1, const float* __restrict__ W2,
        const float* __restrict__ b2, const float* __restrict__ probs,
        const int* __restrict__ mapping, float* __restrict__ outexp) {
    const int b = blockIdx.x;
    const int c = blockIdx.y * 2 + (threadIdx.x >> 5);
    const int lane = threadIdx.x & 31;
    const int e0 = lane * 2;
    const float* hrow = h1 + ((size_t)c * B_ + b) * (HID / 2);
    const float* w2c = W2 + (size_t)c * (HID / 2) * EPC;
    float s0 = b2[c * EPC + e0], s1 = b2[c * EPC + e0 + 1];
    for (int k = 0; k < HID / 2; k += 4) {
        float4 a = *(const float4*)&hrow[k];          // broadcast across lanes
        float2 w0 = *(const float2*)&w2c[(k + 0) * EPC + e0];
        float2 w1 = *(const float2*)&w2c[(k + 1) * EPC + e0];
        float2 w2v = *(const float2*)&w2c[(k + 2) * EPC + e0];
        float2 w3 = *(const float2*)&w2c[(k + 3) * EPC + e0];
        s0 += a.x * w0.x + a.y * w1.x + a.z * w2v.x + a.w * w3.x;
        s1 += a.x * w0.y + a.y * w1.y + a.z * w2v.y + a.w * w3.y;
    }
    const float wgt = probs[b * NC + c];
    const float v0 = wgt / (1.f + expf(-s0));
    const float v1 = wgt / (1.f + expf(-s1));
    const int m0 = mapping[c * EPC + e0], m1 = mapping[c * EPC + e0 + 1];
    atomicAdd(&outexp[(size_t)b * NE + m0], v0);
    atomicAdd(&outexp[(size_t)b * NE + m1], v1);
}

// ===========================================================================
extern "C" void kernel_launch(void* const* d_in, const int* in_sizes, int n_in,
                              void* d_out, int out_size, void* d_ws, size_t ws_size,
                              hipStream_t stream) {
    const float* obs   = (const float*)d_in[0];
    const float* k1    = (const float*)d_in[1];
    const float* cb1   = (const float*)d_in[2];
    const float* k2    = (const float*)d_in[3];
    const float* cb2   = (const float*)d_in[4];
    const float* k3    = (const float*)d_in[5];
    const float* cb3   = (const float*)d_in[6];
    const float* Wproj = (const float*)d_in[7];
    const float* bproj = (const float*)d_in[8];
    const float* Wcat  = (const float*)d_in[9];
    const float* bcat  = (const float*)d_in[10];
    const float* W1    = (const float*)d_in[11];
    const float* b1    = (const float*)d_in[12];
    const float* W2    = (const float*)d_in[13];
    const float* b2    = (const float*)d_in[14];
    const int*   mapping = (const int*)d_in[15];

    float* out    = (float*)d_out;
    float* logits = out;                       // [256*16]
    float* outexp = out + B_ * NC;             // [256*512]
    float* hidden = out + B_ * NC + B_ * NE;   // [256*1024]

    // workspace layout (≈21.7 MB needed):
    char* ws = (char*)d_ws;
    float* x1    = (float*)ws;                     // [256,32,20,20] 13,107,200 B
    float* x2    = (float*)(ws + 13107200);        // [256,64,9,9]    5,308,416 B
    float* feats = (float*)(ws + 18415616);        // [256,3136]      3,211,264 B
    float* probs = (float*)(ws + 21626880);        // [256,16]           16,384 B
    float* accum = (float*)(ws + 21643264);        // [256,1024]      1,048,576 B
    float* h1    = (float*)ws;                     // reuse x1 region (dead after conv2)

    hipMemsetAsync(outexp, 0, (size_t)B_ * NE * sizeof(float), stream);
    hipMemsetAsync(accum, 0, (size_t)B_ * HID * sizeof(float), stream);

    conv1_kernel<<<dim3(10, B_), 320, 0, stream>>>(obs, k1, cb1, x1);
    conv2_kernel<<<dim3(B_), 288, 0, stream>>>(x1, k2, cb2, x2);
    conv3_kernel<<<dim3(B_), 224, 0, stream>>>(x2, k3, cb3, feats);
    proj_gemm_kernel<<<dim3(8, 4, 16), 256, 0, stream>>>(feats, Wproj, accum);
    proj_epi_kernel<<<dim3(256), 256, 0, stream>>>(accum, bproj, hidden);
    cat_softmax_kernel<<<dim3(B_), 256, 0, stream>>>(hidden, Wcat, bcat, logits, probs);
    expert1_gemm_kernel<<<dim3(4, 4, 16), 256, 0, stream>>>(hidden, W1, b1, h1);
    expert2_fused_kernel<<<dim3(B_, 8), 64, 0, stream>>>(h1, W2, b2, probs, mapping, outexp);
}

// Round 3
// 408.824 us; speedup vs baseline: 1.8739x; 1.8739x over previous
//
#include <hip/hip_runtime.h>
#include <hip/hip_bf16.h>

// ---------------------------------------------------------------------------
// r3: bf16-MFMA for conv1 (implicit GEMM), proj, expert1, expert2.
//     conv2/conv3 remain fp32 (next round). fp32->bf16 RNE in-kernel.
// Outputs (flat f32): logits[256*16] | expert_probs[256*512] | hidden[256*1024]
// ---------------------------------------------------------------------------

#define B_    256
#define CIN   12
#define HH    84
#define WW    84
#define HID   1024
#define NC    16
#define NE    512
#define EPC   64
#define FLAT  3136

typedef short short8 __attribute__((ext_vector_type(8)));
typedef short short4_t __attribute__((ext_vector_type(4)));
typedef float f32x4 __attribute__((ext_vector_type(4)));

__device__ __forceinline__ short f2bf(float x) {   // round-to-nearest-even bf16
    unsigned int u = __float_as_uint(x);
    u = (u + 0x7FFFu + ((u >> 16) & 1u)) >> 16;
    return (short)u;
}

// ===================== cast k1 [32*768] fp32 -> bf16 =======================
__global__ __launch_bounds__(256) void cast_k1_kernel(
        const float* __restrict__ k1, short* __restrict__ k1bf) {
    int i = blockIdx.x * 256 + threadIdx.x;
    if (i < 32 * 768) k1bf[i] = f2bf(k1[i]);
}

// ========== conv1 as implicit GEMM, bf16 MFMA: M=102400 N=32 K=768 =========
// grid 1600, block 256 (4 waves). Wave: one 16-row m-frag x 32 oc.
// k = ic*64 + ky*8 + kx; a-frag = contiguous 8 floats of an obs row (cast).
__global__ __launch_bounds__(256) void conv1_mfma_kernel(
        const float* __restrict__ obs, const short* __restrict__ k1bf,
        const float* __restrict__ cb1, float* __restrict__ x1) {
    const int tid = threadIdx.x;
    const int w = tid >> 6, l = tid & 63;
    const int lr = l & 15, g = l >> 4;
    const int mfb = blockIdx.x * 64 + w * 16;

    const int row_a = mfb + lr;                 // A row this lane loads
    const int b_a = row_a / 400;
    const int p_a = row_a % 400;
    const int oy = p_a / 20, ox = p_a % 20;
    const float* abase = obs + (size_t)b_a * (CIN * HH * WW) + (4 * oy) * WW + 4 * ox;
    const short* bb0 = k1bf + lr * 768;         // oc = lr
    const short* bb1 = k1bf + (16 + lr) * 768;  // oc = 16+lr

    f32x4 acc0 = {0.f, 0.f, 0.f, 0.f}, acc1 = {0.f, 0.f, 0.f, 0.f};
    #pragma unroll 4
    for (int s = 0; s < 24; ++s) {
        const int idx = s * 4 + g;              // (ic,ky) pair for this lane-grp
        const int ic = idx >> 3, ky = idx & 7;
        const float* ap = abase + ic * (HH * WW) + ky * WW;
        float4 f0 = *(const float4*)ap;
        float4 f1 = *(const float4*)(ap + 4);
        short8 a;
        a[0] = f2bf(f0.x); a[1] = f2bf(f0.y); a[2] = f2bf(f0.z); a[3] = f2bf(f0.w);
        a[4] = f2bf(f1.x); a[5] = f2bf(f1.y); a[6] = f2bf(f1.z); a[7] = f2bf(f1.w);
        short8 b0 = *(const short8*)(bb0 + s * 32 + g * 8);
        short8 b1 = *(const short8*)(bb1 + s * 32 + g * 8);
        acc0 = __builtin_amdgcn_mfma_f32_16x16x32_bf16(a, b0, acc0, 0, 0, 0);
        acc1 = __builtin_amdgcn_mfma_f32_16x16x32_bf16(a, b1, acc1, 0, 0, 0);
    }
    // D: row = mfb + g*4 + r, col = lr (acc0) / 16+lr (acc1)
    #pragma unroll
    for (int r = 0; r < 4; ++r) {
        const int ro = mfb + g * 4 + r;
        const int b_o = ro / 400, p_o = ro % 400;
        float* xp = x1 + (size_t)b_o * 32 * 400 + p_o;
        xp[(size_t)lr * 400]        = fmaxf(acc0[r] + cb1[lr], 0.f);
        xp[(size_t)(16 + lr) * 400] = fmaxf(acc1[r] + cb1[16 + lr], 0.f);
    }
}

// ============================ conv2: 32->64, 4x4, s2, relu (fp32) ==========
__global__ __launch_bounds__(288) void conv2_kernel(
        const float* __restrict__ x1, const float* __restrict__ k2,
        const float* __restrict__ cb2, float* __restrict__ x2) {
    __shared__ float slab[32][20][20];
    const int b = blockIdx.x, tid = threadIdx.x;
    const float* src = x1 + (size_t)b * 32 * 400;
    float4* s4 = (float4*)&slab[0][0][0];
    const float4* g4 = (const float4*)src;
    for (int l = tid; l < 3200; l += 288) s4[l] = g4[l];
    __syncthreads();

    const int ocp = tid / 9, oy = tid % 9;
    const int oc0 = 2 * ocp;
    float acc[2][9];
    #pragma unroll
    for (int o = 0; o < 2; ++o) {
        float bv = cb2[oc0 + o];
        #pragma unroll
        for (int i = 0; i < 9; ++i) acc[o][i] = bv;
    }
    for (int ic = 0; ic < 32; ++ic) {
        float wvv[2][16];
        const float* wp = k2 + oc0 * 512 + ic * 16;
        #pragma unroll
        for (int o = 0; o < 2; ++o)
            #pragma unroll
            for (int ky = 0; ky < 4; ++ky) {
                float4 t = *(const float4*)(wp + o * 512 + 4 * ky);
                wvv[o][4*ky] = t.x; wvv[o][4*ky+1] = t.y;
                wvv[o][4*ky+2] = t.z; wvv[o][4*ky+3] = t.w;
            }
        #pragma unroll
        for (int ky = 0; ky < 4; ++ky) {
            const int row = 2 * oy + ky;
            float rf[20];
            const float4* rp = (const float4*)&slab[ic][row][0];
            #pragma unroll
            for (int q = 0; q < 5; ++q) {
                float4 t = rp[q];
                rf[4*q] = t.x; rf[4*q+1] = t.y; rf[4*q+2] = t.z; rf[4*q+3] = t.w;
            }
            #pragma unroll
            for (int ox = 0; ox < 9; ++ox)
                #pragma unroll
                for (int kx = 0; kx < 4; ++kx) {
                    float v = rf[2 * ox + kx];
                    acc[0][ox] += v * wvv[0][4 * ky + kx];
                    acc[1][ox] += v * wvv[1][4 * ky + kx];
                }
        }
    }
    #pragma unroll
    for (int o = 0; o < 2; ++o) {
        float* dst = x2 + ((size_t)(b * 64 + oc0 + o) * 9 + oy) * 9;
        #pragma unroll
        for (int ox = 0; ox < 9; ++ox) dst[ox] = fmaxf(acc[o][ox], 0.f);
    }
}

// ================== conv3: 64->64, 3x3, s1, relu -> feats bf16 =============
__global__ __launch_bounds__(224) void conv3_kernel(
        const float* __restrict__ x2, const float* __restrict__ k3,
        const float* __restrict__ cb3, short* __restrict__ featsbf) {
    __shared__ float slab[64][9][12];
    const int b = blockIdx.x, tid = threadIdx.x;
    for (int l = tid; l < 64 * 9 * 12; l += 224) {
        int ic = l / 108, rest = l % 108, r = rest / 12, x = rest % 12;
        slab[ic][r][x] = (x < 9) ? x2[((size_t)(b * 64 + ic) * 9 + r) * 9 + x] : 0.f;
    }
    __syncthreads();

    const int ocp = tid / 7, oy = tid % 7;
    const int oc0 = 2 * ocp;
    float acc[2][7];
    #pragma unroll
    for (int o = 0; o < 2; ++o) {
        float bv = cb3[oc0 + o];
        #pragma unroll
        for (int i = 0; i < 7; ++i) acc[o][i] = bv;
    }
    for (int ic = 0; ic < 64; ++ic) {
        float wv2[2][9];
        const float* wp = k3 + oc0 * 576 + ic * 9;
        #pragma unroll
        for (int j = 0; j < 9; ++j) { wv2[0][j] = wp[j]; wv2[1][j] = wp[576 + j]; }
        #pragma unroll
        for (int ky = 0; ky < 3; ++ky) {
            const int row = oy + ky;
            float rf[12];
            const float4* rp = (const float4*)&slab[ic][row][0];
            #pragma unroll
            for (int q = 0; q < 3; ++q) {
                float4 t = rp[q];
                rf[4*q] = t.x; rf[4*q+1] = t.y; rf[4*q+2] = t.z; rf[4*q+3] = t.w;
            }
            #pragma unroll
            for (int ox = 0; ox < 7; ++ox)
                #pragma unroll
                for (int kx = 0; kx < 3; ++kx) {
                    float v = rf[ox + kx];
                    acc[0][ox] += v * wv2[0][3 * ky + kx];
                    acc[1][ox] += v * wv2[1][3 * ky + kx];
                }
        }
    }
    #pragma unroll
    for (int o = 0; o < 2; ++o) {
        short* dst = featsbf + (size_t)b * FLAT + (oc0 + o) * 49 + oy * 7;
        #pragma unroll
        for (int ox = 0; ox < 7; ++ox) dst[ox] = f2bf(fmaxf(acc[o][ox], 0.f));
    }
}

// ============ proj MFMA: hidden-pre = feats_bf @ Wproj, split-K=4 ==========
// grid (nb=64 -> n0=bx*16, kz=by in 0..3), block 256 (4 waves).
// Wave: 4 m-frags (covers M=256) x 16 cols. Writes accum4[kz][256][1024].
__global__ __launch_bounds__(256) void proj_mfma_kernel(
        const short* __restrict__ Abf, const float* __restrict__ W,
        float* __restrict__ accum4) {
    __shared__ __align__(16) short lbt[16][40];   // Bt tile: [n][32k + pad]
    const int tid = threadIdx.x;
    const int w = tid >> 6, l = tid & 63, lr = l & 15, g = l >> 4;
    const int n0 = blockIdx.x * 16;
    const int kz = blockIdx.y;
    const int sb = kz * 24 + (kz < 2 ? kz : 2);
    const int ns = (kz < 2) ? 25 : 24;            // 25+25+24+24 = 98 = 3136/32
    const int krp = tid >> 4, nn = tid & 15;      // staging assignment

    f32x4 acc[4] = {};
    const short* arow[4];
    #pragma unroll
    for (int i = 0; i < 4; ++i)
        arow[i] = Abf + (size_t)(w * 64 + i * 16 + lr) * FLAT;

    for (int s = sb; s < sb + ns; ++s) {
        const int k0 = s * 32;
        {   // stage 32k x 16n of W (fp32 [3136][1024]) transposed+cast
            const float* wp = W + (size_t)(k0 + 2 * krp) * HID + n0 + nn;
            unsigned int lo = (unsigned short)f2bf(wp[0]);
            unsigned int hi = (unsigned short)f2bf(wp[HID]);
            *(unsigned int*)&lbt[nn][2 * krp] = lo | (hi << 16);
        }
        __syncthreads();
        short8 b = *(const short8*)&lbt[lr][g * 8];
        #pragma unroll
        for (int i = 0; i < 4; ++i) {
            short8 a = *(const short8*)(arow[i] + k0 + g * 8);
            acc[i] = __builtin_amdgcn_mfma_f32_16x16x32_bf16(a, b, acc[i], 0, 0, 0);
        }
        __syncthreads();
    }
    float* dst = accum4 + (size_t)kz * (B_ * HID);
    #pragma unroll
    for (int i = 0; i < 4; ++i)
        #pragma unroll
        for (int r = 0; r < 4; ++r)
            dst[(size_t)(w * 64 + i * 16 + g * 4 + r) * HID + n0 + lr] = acc[i][r];
}

// ===== proj epilogue: hidden = relu(sum_kz accum4 + bproj) -> f32 + bf16 ===
__global__ __launch_bounds__(256) void proj_epi2_kernel(
        const float* __restrict__ accum4, const float* __restrict__ bproj,
        float* __restrict__ hidden, short* __restrict__ hbf) {
    const int i = blockIdx.x * 256 + threadIdx.x;      // 65536 float4 groups
    float4 v = *(const float4*)&accum4[4 * i];
    #pragma unroll
    for (int kz = 1; kz < 4; ++kz) {
        float4 t = *(const float4*)&accum4[(size_t)kz * (B_ * HID) + 4 * i];
        v.x += t.x; v.y += t.y; v.z += t.z; v.w += t.w;
    }
    float4 bb = *(const float4*)&bproj[(4 * i) & (HID - 1)];
    float4 r;
    r.x = fmaxf(v.x + bb.x, 0.f); r.y = fmaxf(v.y + bb.y, 0.f);
    r.z = fmaxf(v.z + bb.z, 0.f); r.w = fmaxf(v.w + bb.w, 0.f);
    *(float4*)&hidden[4 * i] = r;
    short4_t h; h[0] = f2bf(r.x); h[1] = f2bf(r.y); h[2] = f2bf(r.z); h[3] = f2bf(r.w);
    *(short4_t*)&hbf[4 * i] = h;
}

// ============ category head + softmax: logits & probs (fp32) ===============
__global__ __launch_bounds__(256) void cat_softmax_kernel(
        const float* __restrict__ hidden, const float* __restrict__ Wcat,
        const float* __restrict__ bcat, float* __restrict__ logits,
        float* __restrict__ probs) {
    __shared__ float red[256];
    __shared__ float lvals[16];
    const int b = blockIdx.x, tid = threadIdx.x;
    const int cc = tid & 15, kq = tid >> 4;
    const float* hrow = hidden + (size_t)b * HID;
    float p = 0.f;
    for (int t = 0; t < 64; ++t) {
        int k = kq * 64 + t;
        p += hrow[k] * Wcat[k * NC + cc];
    }
    red[tid] = p;
    __syncthreads();
    if (tid < 16) {
        float s = bcat[tid];
        #pragma unroll
        for (int q = 0; q < 16; ++q) s += red[q * 16 + tid];
        logits[b * NC + tid] = s;
        lvals[tid] = s;
    }
    __syncthreads();
    if (tid < 16) {
        float m = lvals[0];
        #pragma unroll
        for (int q = 1; q < 16; ++q) m = fmaxf(m, lvals[q]);
        float sum = 0.f;
        #pragma unroll
        for (int q = 0; q < 16; ++q) sum += expf(lvals[q] - m);
        probs[b * NC + tid] = expf(lvals[tid] - m) / sum;
    }
}

// ====== expert1 MFMA: h1[c] = relu(hidden_bf @ W1[c] + b1[c]) -> bf16 ======
// grid (nb=16 -> n0=bx*32, c=by), block 256. Wave: 4 m-frags x 2 n-frags.
__global__ __launch_bounds__(256) void expert1_mfma_kernel(
        const short* __restrict__ Hbf, const float* __restrict__ W1,
        const float* __restrict__ b1, short* __restrict__ h1bf) {
    __shared__ __align__(16) short lbt[32][40];
    const int tid = threadIdx.x;
    const int w = tid >> 6, l = tid & 63, lr = l & 15, g = l >> 4;
    const int n0 = blockIdx.x * 32;
    const int c  = blockIdx.y;
    const float* Wc = W1 + (size_t)c * (HID * (HID / 2));

    f32x4 acc[4][2] = {};
    const short* arow[4];
    #pragma unroll
    for (int i = 0; i < 4; ++i)
        arow[i] = Hbf + (size_t)(w * 64 + i * 16 + lr) * HID;

    for (int s = 0; s < 32; ++s) {
        const int k0 = s * 32;
        #pragma unroll
        for (int it = 0; it < 2; ++it) {   // stage 32k x 32n
            const int idx = tid + it * 256;
            const int krp = idx >> 5, nn = idx & 31;
            const float* wp = Wc + (size_t)(k0 + 2 * krp) * (HID / 2) + n0 + nn;
            unsigned int lo = (unsigned short)f2bf(wp[0]);
            unsigned int hi = (unsigned short)f2bf(wp[HID / 2]);
            *(unsigned int*)&lbt[nn][2 * krp] = lo | (hi << 16);
        }
        __syncthreads();
        short8 b0 = *(const short8*)&lbt[lr][g * 8];
        short8 b1v = *(const short8*)&lbt[16 + lr][g * 8];
        #pragma unroll
        for (int i = 0; i < 4; ++i) {
            short8 a = *(const short8*)(arow[i] + k0 + g * 8);
            acc[i][0] = __builtin_amdgcn_mfma_f32_16x16x32_bf16(a, b0, acc[i][0], 0, 0, 0);
            acc[i][1] = __builtin_amdgcn_mfma_f32_16x16x32_bf16(a, b1v, acc[i][1], 0, 0, 0);
        }
        __syncthreads();
    }
    #pragma unroll
    for (int i = 0; i < 4; ++i)
        #pragma unroll
        for (int j = 0; j < 2; ++j)
            #pragma unroll
            for (int r = 0; r < 4; ++r) {
                const int m = w * 64 + i * 16 + g * 4 + r;
                const int col = n0 + j * 16 + lr;
                float v = fmaxf(acc[i][j][r] + b1[c * (HID / 2) + col], 0.f);
                h1bf[((size_t)c * B_ + m) * (HID / 2) + col] = f2bf(v);
            }
}

// == expert2 MFMA fused: sigmoid(h1@W2+b2)*probs -> atomic scatter to out ===
// grid (mb=16, c=16), block 256. Block: 16 rows x 64 cols; wave = n-frag.
__global__ __launch_bounds__(256) void expert2_mfma_kernel(
        const short* __restrict__ h1bf, const float* __restrict__ W2,
        const float* __restrict__ b2, const float* __restrict__ probs,
        const int* __restrict__ mapping, float* __restrict__ outexp) {
    __shared__ __align__(16) short lbt[64][40];
    const int tid = threadIdx.x;
    const int w = tid >> 6, l = tid & 63, lr = l & 15, g = l >> 4;
    const int mfb = blockIdx.x * 16;
    const int c = blockIdx.y;
    const float* Wc = W2 + (size_t)c * ((HID / 2) * EPC);
    const short* arow = h1bf + ((size_t)c * B_ + mfb + lr) * (HID / 2);

    f32x4 acc = {};
    for (int s = 0; s < 16; ++s) {
        const int k0 = s * 32;
        #pragma unroll
        for (int it = 0; it < 4; ++it) {   // stage 32k x 64n
            const int idx = tid + it * 256;
            const int krp = idx >> 6, nn = idx & 63;
            const float* wp = Wc + (size_t)(k0 + 2 * krp) * EPC + nn;
            unsigned int lo = (unsigned short)f2bf(wp[0]);
            unsigned int hi = (unsigned short)f2bf(wp[EPC]);
            *(unsigned int*)&lbt[nn][2 * krp] = lo | (hi << 16);
        }
        __syncthreads();
        short8 b = *(const short8*)&lbt[w * 16 + lr][g * 8];
        short8 a = *(const short8*)(arow + k0 + g * 8);
        acc = __builtin_amdgcn_mfma_f32_16x16x32_bf16(a, b, acc, 0, 0, 0);
        __syncthreads();
    }
    const int e = w * 16 + lr;
    const float bb = b2[c * EPC + e];
    const int tgt = mapping[c * EPC + e];
    #pragma unroll
    for (int r = 0; r < 4; ++r) {
        const int m = mfb + g * 4 + r;
        const float lg = acc[r] + bb;
        const float v = probs[m * NC + c] / (1.f + expf(-lg));
        atomicAdd(&outexp[(size_t)m * NE + tgt], v);
    }
}

// ===========================================================================
extern "C" void kernel_launch(void* const* d_in, const int* in_sizes, int n_in,
                              void* d_out, int out_size, void* d_ws, size_t ws_size,
                              hipStream_t stream) {
    const float* obs   = (const float*)d_in[0];
    const float* k1    = (const float*)d_in[1];
    const float* cb1   = (const float*)d_in[2];
    const float* k2    = (const float*)d_in[3];
    const float* cb2   = (const float*)d_in[4];
    const float* k3    = (const float*)d_in[5];
    const float* cb3   = (const float*)d_in[6];
    const float* Wproj = (const float*)d_in[7];
    const float* bproj = (const float*)d_in[8];
    const float* Wcat  = (const float*)d_in[9];
    const float* bcat  = (const float*)d_in[10];
    const float* W1    = (const float*)d_in[11];
    const float* b1    = (const float*)d_in[12];
    const float* W2    = (const float*)d_in[13];
    const float* b2    = (const float*)d_in[14];
    const int*   mapping = (const int*)d_in[15];

    float* out    = (float*)d_out;
    float* logits = out;                       // [256*16]
    float* outexp = out + B_ * NC;             // [256*512]
    float* hidden = out + B_ * NC + B_ * NE;   // [256*1024]

    // ws layout (proven budget >= 22.69MB from r2; this uses ~20.1MB):
    //  [0,13107200): x1 fp32 (conv1->conv2); REUSED after conv2:
    //     accum4 @0 (4,194,304 = 4x256x1024 f32)
    //     h1_bf  @4,194,304 (4,194,304 = 16x256x512 bf16)
    //     hid_bf @8,388,608 (524,288)
    //  [13107200,18415616): x2 fp32
    //  [18415616,20021248): feats_bf
    //  [20021248,20037632): probs
    //  [20037632,20086784): k1_bf
    char* ws = (char*)d_ws;
    float* x1      = (float*)ws;
    float* accum4  = (float*)ws;
    short* h1bf    = (short*)(ws + 4194304);
    short* hidbf   = (short*)(ws + 8388608);
    float* x2      = (float*)(ws + 13107200);
    short* featsbf = (short*)(ws + 18415616);
    float* probs   = (float*)(ws + 20021248);
    short* k1bf    = (short*)(ws + 20037632);

    hipMemsetAsync(outexp, 0, (size_t)B_ * NE * sizeof(float), stream);

    cast_k1_kernel<<<dim3(96), 256, 0, stream>>>(k1, k1bf);
    conv1_mfma_kernel<<<dim3(1600), 256, 0, stream>>>(obs, k1bf, cb1, x1);
    conv2_kernel<<<dim3(B_), 288, 0, stream>>>(x1, k2, cb2, x2);
    conv3_kernel<<<dim3(B_), 224, 0, stream>>>(x2, k3, cb3, featsbf);
    proj_mfma_kernel<<<dim3(64, 4), 256, 0, stream>>>(featsbf, Wproj, accum4);
    proj_epi2_kernel<<<dim3(256), 256, 0, stream>>>(accum4, bproj, hidden, hidbf);
    cat_softmax_kernel<<<dim3(B_), 256, 0, stream>>>(hidden, Wcat, bcat, logits, probs);
    expert1_mfma_kernel<<<dim3(16, 16), 256, 0, stream>>>(hidbf, W1, b1, h1bf);
    expert2_mfma_kernel<<<dim3(16, 16), 256, 0, stream>>>(h1bf, W2, b2, probs, mapping, outexp);
}

// Round 4
// 373.750 us; speedup vs baseline: 2.0497x; 1.0938x over previous
//
#include <hip/hip_runtime.h>
#include <hip/hip_bf16.h>

// ---------------------------------------------------------------------------
// r4: full bf16-MFMA pipeline, NHWC bf16 activations, pre-transposed weights.
//   conv1: LDS-slab implicit GEMM (obs fp32 -> bf16 slab once)
//   conv2/conv3: register-only implicit GEMM, contiguous 16B frags
//   proj/expert1/expert2: register-only GEMM from bf16 [n][k] weights
// Outputs (flat f32): logits[256*16] | expert_probs[256*512] | hidden[256*1024]
// ---------------------------------------------------------------------------

#define B_    256
#define CIN   12
#define HH    84
#define WW    84
#define HID   1024
#define NC    16
#define NE    512
#define EPC   64
#define FLAT  3136

typedef short short8 __attribute__((ext_vector_type(8)));
typedef short short4_t __attribute__((ext_vector_type(4)));
typedef float f32x4 __attribute__((ext_vector_type(4)));

__device__ __forceinline__ short f2bf(float x) {   // RNE bf16
    unsigned int u = __float_as_uint(x);
    u = (u + 0x7FFFu + ((u >> 16) & 1u)) >> 16;
    return (short)u;
}

// ============ prep: k1 cast; k2,k3 reorder (oc)(ky,kx,ic) + cast ===========
__global__ __launch_bounds__(256) void prep_weights_kernel(
        const float* __restrict__ k1, const float* __restrict__ k2,
        const float* __restrict__ k3, short* __restrict__ k1bf,
        short* __restrict__ k2t, short* __restrict__ k3t) {
    int i = blockIdx.x * 256 + threadIdx.x;
    if (i < 24576) {                       // k1: layout already (ic,ky,kx)
        k1bf[i] = f2bf(k1[i]);
    } else if (i < 24576 + 32768) {        // k2t[oc][tap16][ic32]
        int j = i - 24576;
        int oc = j >> 9, rem = j & 511, tap = rem >> 5, ic = rem & 31;
        k2t[j] = f2bf(k2[oc * 512 + ic * 16 + tap]);
    } else if (i < 24576 + 32768 + 36864) { // k3t[oc][tap9][ic64]
        int j = i - 57344;
        int oc = j / 576, rem = j % 576, tap = rem >> 6, ic = rem & 63;
        k3t[j] = f2bf(k3[oc * 576 + ic * 9 + tap]);
    }
}

// ======= generic tiled transpose+cast: src f32 [z][R][C] -> dst bf16 [z][C][R]
__global__ __launch_bounds__(256) void transpose_cast_kernel(
        const float* __restrict__ src, short* __restrict__ dst,
        int R, int C, long sbs, long dbs) {
    __shared__ float tile[32][33];
    const int c0 = blockIdx.x * 32, r0 = blockIdx.y * 32, z = blockIdx.z;
    const int tx = threadIdx.x & 31, ty = threadIdx.x >> 5;
    const float* s = src + (size_t)z * sbs;
    short* d = dst + (size_t)z * dbs;
    #pragma unroll
    for (int it = 0; it < 4; ++it)
        tile[ty + it * 8][tx] = s[(size_t)(r0 + ty + it * 8) * C + c0 + tx];
    __syncthreads();
    #pragma unroll
    for (int it = 0; it < 4; ++it) {
        int j = ty + it * 8;               // col of src
        d[(size_t)(c0 + j) * R + r0 + tx] = f2bf(tile[tx][j]);
    }
}

// ========== conv1: LDS-slab implicit GEMM. grid (oyq=4, b=256), 448 thr ====
// Block: 5 output rows x 20 ox = 100 pixels; 7 waves x 16-row frags (pad 112).
// K=768, k=(ic,ky,kx). Slab: input rows 20*oyq..+23 as bf16 [12][24][88].
__global__ __launch_bounds__(448) void conv1_mfma_kernel(
        const float* __restrict__ obs, const short* __restrict__ k1bf,
        const float* __restrict__ cb1, short* __restrict__ x1bf) {
    __shared__ short slab[CIN][24][88];
    const int oyq = blockIdx.x, b = blockIdx.y;
    const int tid = threadIdx.x;

    // stage: 12ch x 24 rows x 84 cols fp32 -> bf16 slab (coalesced float4)
    const float* src = obs + (size_t)b * (CIN * HH * WW) + (20 * oyq) * WW;
    for (int l = tid; l < CIN * 24 * 21; l += 448) {
        int ic = l / 504, rem = l % 504, r = rem / 21, c4 = rem % 21;
        float4 f = *(const float4*)(src + (size_t)ic * (HH * WW) + r * WW + 4 * c4);
        short4_t v;
        v[0] = f2bf(f.x); v[1] = f2bf(f.y); v[2] = f2bf(f.z); v[3] = f2bf(f.w);
        *(short4_t*)&slab[ic][r][4 * c4] = v;
    }
    __syncthreads();

    const int w = tid >> 6, l = tid & 63, lr = l & 15, g = l >> 4;
    const int p = w * 16 + lr;
    const int pw = (p < 100) ? p : 99;          // clamp A rows of pad frag
    const int oy_l = pw / 20, ox = pw % 20;
    const short* bb0 = k1bf + lr * 768;
    const short* bb1 = k1bf + (16 + lr) * 768;

    f32x4 acc0 = {0.f, 0.f, 0.f, 0.f}, acc1 = {0.f, 0.f, 0.f, 0.f};
    #pragma unroll 4
    for (int s = 0; s < 24; ++s) {
        const int idx = s * 4 + g;              // (ic,ky)
        const int ic = idx >> 3, ky = idx & 7;
        const short* ap = &slab[ic][4 * oy_l + ky][4 * ox];
        short8 a;
        *(short4_t*)&a       = *(const short4_t*)ap;
        *((short4_t*)&a + 1) = *(const short4_t*)(ap + 4);
        short8 b0 = *(const short8*)(bb0 + s * 32 + g * 8);
        short8 b1 = *(const short8*)(bb1 + s * 32 + g * 8);
        acc0 = __builtin_amdgcn_mfma_f32_16x16x32_bf16(a, b0, acc0, 0, 0, 0);
        acc1 = __builtin_amdgcn_mfma_f32_16x16x32_bf16(a, b1, acc1, 0, 0, 0);
    }
    const float c0v = cb1[lr], c1v = cb1[16 + lr];
    #pragma unroll
    for (int r = 0; r < 4; ++r) {
        const int ro = w * 16 + g * 4 + r;      // pixel in block
        if (ro < 100) {
            const int oy_g = 5 * oyq + ro / 20, ox_g = ro % 20;
            short* dst = x1bf + ((size_t)(b * 20 + oy_g) * 20 + ox_g) * 32;
            dst[lr]      = f2bf(fmaxf(acc0[r] + c0v, 0.f));
            dst[16 + lr] = f2bf(fmaxf(acc1[r] + c1v, 0.f));
        }
    }
}

// ====== conv2: register implicit GEMM. M=20736 N=64 K=512. grid 1296x64 ====
__global__ __launch_bounds__(64) void conv2_mfma_kernel(
        const short* __restrict__ x1bf, const short* __restrict__ k2t,
        const float* __restrict__ cb2, short* __restrict__ x2bf) {
    const int l = threadIdx.x, lr = l & 15, g = l >> 4;
    const int mfb = blockIdx.x * 16;
    const int ro = mfb + lr;
    const int b = ro / 81, pp = ro % 81, oy = pp / 9, ox = pp % 9;
    const short* abase = x1bf + (size_t)b * 12800;

    f32x4 acc[4] = {};
    #pragma unroll 4
    for (int s = 0; s < 16; ++s) {              // tap (ky,kx), 32 ic each
        const int ky = s >> 2, kx = s & 3;
        short8 a = *(const short8*)(abase +
            ((size_t)((2 * oy + ky) * 20 + 2 * ox + kx)) * 32 + g * 8);
        #pragma unroll
        for (int nf = 0; nf < 4; ++nf) {
            short8 bv = *(const short8*)(k2t + (size_t)(nf * 16 + lr) * 512 + s * 32 + g * 8);
            acc[nf] = __builtin_amdgcn_mfma_f32_16x16x32_bf16(a, bv, acc[nf], 0, 0, 0);
        }
    }
    #pragma unroll
    for (int nf = 0; nf < 4; ++nf) {
        const int col = nf * 16 + lr;
        const float bb = cb2[col];
        #pragma unroll
        for (int r = 0; r < 4; ++r) {
            const int roo = mfb + g * 4 + r;
            x2bf[(size_t)roo * 64 + col] = f2bf(fmaxf(acc[nf][r] + bb, 0.f));
        }
    }
}

// ====== conv3: register implicit GEMM. M=12544 N=64 K=576. grid 784x64 =====
__global__ __launch_bounds__(64) void conv3_mfma_kernel(
        const short* __restrict__ x2bf, const short* __restrict__ k3t,
        const float* __restrict__ cb3, short* __restrict__ featsbf) {
    const int l = threadIdx.x, lr = l & 15, g = l >> 4;
    const int mfb = blockIdx.x * 16;
    const int ro = mfb + lr;
    const int b = ro / 49, pp = ro % 49, oy = pp / 7, ox = pp % 7;
    const short* abase = x2bf + (size_t)b * 5184;

    f32x4 acc[4] = {};
    #pragma unroll 4
    for (int s = 0; s < 18; ++s) {              // (tap=s>>1, ic-half=s&1)
        const int tap = s >> 1, ich = s & 1;
        const int ky = tap / 3, kx = tap % 3;
        short8 a = *(const short8*)(abase +
            ((size_t)((oy + ky) * 9 + ox + kx)) * 64 + ich * 32 + g * 8);
        #pragma unroll
        for (int nf = 0; nf < 4; ++nf) {
            short8 bv = *(const short8*)(k3t + (size_t)(nf * 16 + lr) * 576 + s * 32 + g * 8);
            acc[nf] = __builtin_amdgcn_mfma_f32_16x16x32_bf16(a, bv, acc[nf], 0, 0, 0);
        }
    }
    #pragma unroll
    for (int nf = 0; nf < 4; ++nf) {
        const int col = nf * 16 + lr;
        const float bb = cb3[col];
        #pragma unroll
        for (int r = 0; r < 4; ++r) {
            const int roo = mfb + g * 4 + r;
            const int b_o = roo / 49, p_o = roo % 49;
            featsbf[(size_t)b_o * FLAT + col * 49 + p_o] =
                f2bf(fmaxf(acc[nf][r] + bb, 0.f));
        }
    }
}

// ====== proj: hidden = relu(feats @ Wproj + b). grid (nb=64, mb=8), 64 thr =
// wave: 2 m-frags (32 rows) x 16 cols, full K=3136. Writes f32 + bf16.
__global__ __launch_bounds__(64) void proj_mfma_kernel(
        const short* __restrict__ Abf, const short* __restrict__ Wt,
        const float* __restrict__ bproj, float* __restrict__ hidden,
        short* __restrict__ hbf) {
    const int l = threadIdx.x, lr = l & 15, g = l >> 4;
    const int n0 = blockIdx.x * 16, m0 = blockIdx.y * 32;
    const short* a0 = Abf + (size_t)(m0 + lr) * FLAT;
    const short* a1 = Abf + (size_t)(m0 + 16 + lr) * FLAT;
    const short* br = Wt + (size_t)(n0 + lr) * FLAT;

    f32x4 acc0 = {}, acc1 = {};
    #pragma unroll 4
    for (int s = 0; s < 98; ++s) {
        const int k = s * 32 + g * 8;
        short8 bv = *(const short8*)(br + k);
        short8 av0 = *(const short8*)(a0 + k);
        short8 av1 = *(const short8*)(a1 + k);
        acc0 = __builtin_amdgcn_mfma_f32_16x16x32_bf16(av0, bv, acc0, 0, 0, 0);
        acc1 = __builtin_amdgcn_mfma_f32_16x16x32_bf16(av1, bv, acc1, 0, 0, 0);
    }
    const int col = n0 + lr;
    const float bb = bproj[col];
    #pragma unroll
    for (int r = 0; r < 4; ++r) {
        const int m = m0 + g * 4 + r;
        float v = fmaxf(acc0[r] + bb, 0.f);
        hidden[(size_t)m * HID + col] = v;
        hbf[(size_t)m * HID + col] = f2bf(v);
        const int m2 = m + 16;
        float v2 = fmaxf(acc1[r] + bb, 0.f);
        hidden[(size_t)m2 * HID + col] = v2;
        hbf[(size_t)m2 * HID + col] = f2bf(v2);
    }
}

// ============ category head + softmax (fp32, unchanged) ====================
__global__ __launch_bounds__(256) void cat_softmax_kernel(
        const float* __restrict__ hidden, const float* __restrict__ Wcat,
        const float* __restrict__ bcat, float* __restrict__ logits,
        float* __restrict__ probs) {
    __shared__ float red[256];
    __shared__ float lvals[16];
    const int b = blockIdx.x, tid = threadIdx.x;
    const int cc = tid & 15, kq = tid >> 4;
    const float* hrow = hidden + (size_t)b * HID;
    float p = 0.f;
    for (int t = 0; t < 64; ++t) {
        int k = kq * 64 + t;
        p += hrow[k] * Wcat[k * NC + cc];
    }
    red[tid] = p;
    __syncthreads();
    if (tid < 16) {
        float s = bcat[tid];
        #pragma unroll
        for (int q = 0; q < 16; ++q) s += red[q * 16 + tid];
        logits[b * NC + tid] = s;
        lvals[tid] = s;
    }
    __syncthreads();
    if (tid < 16) {
        float m = lvals[0];
        #pragma unroll
        for (int q = 1; q < 16; ++q) m = fmaxf(m, lvals[q]);
        float sum = 0.f;
        #pragma unroll
        for (int q = 0; q < 16; ++q) sum += expf(lvals[q] - m);
        probs[b * NC + tid] = expf(lvals[tid] - m) / sum;
    }
}

// === expert1: h1[c]=relu(hidden@W1[c]+b1[c]). grid (nb=16,mb=4,c=16), 64thr =
// wave: 4 m-frags (64 rows) x 2 n-frags (32 cols), K=1024.
__global__ __launch_bounds__(64) void expert1_mfma_kernel(
        const short* __restrict__ Hbf, const short* __restrict__ W1t,
        const float* __restrict__ b1, short* __restrict__ h1bf) {
    const int l = threadIdx.x, lr = l & 15, g = l >> 4;
    const int n0 = blockIdx.x * 32, m0 = blockIdx.y * 64, c = blockIdx.z;
    const short* ar[4];
    #pragma unroll
    for (int i = 0; i < 4; ++i) ar[i] = Hbf + (size_t)(m0 + i * 16 + lr) * HID;
    const short* br0 = W1t + (size_t)c * (512 * HID) + (size_t)(n0 + lr) * HID;
    const short* br1 = br0 + 16 * HID;

    f32x4 acc[4][2] = {};
    #pragma unroll 2
    for (int s = 0; s < 32; ++s) {
        const int k = s * 32 + g * 8;
        short8 b0 = *(const short8*)(br0 + k);
        short8 b1v = *(const short8*)(br1 + k);
        #pragma unroll
        for (int i = 0; i < 4; ++i) {
            short8 a = *(const short8*)(ar[i] + k);
            acc[i][0] = __builtin_amdgcn_mfma_f32_16x16x32_bf16(a, b0, acc[i][0], 0, 0, 0);
            acc[i][1] = __builtin_amdgcn_mfma_f32_16x16x32_bf16(a, b1v, acc[i][1], 0, 0, 0);
        }
    }
    #pragma unroll
    for (int j = 0; j < 2; ++j) {
        const int col = n0 + j * 16 + lr;
        const float bb = b1[c * 512 + col];
        #pragma unroll
        for (int i = 0; i < 4; ++i)
            #pragma unroll
            for (int r = 0; r < 4; ++r) {
                const int m = m0 + i * 16 + g * 4 + r;
                h1bf[((size_t)c * B_ + m) * 512 + col] =
                    f2bf(fmaxf(acc[i][j][r] + bb, 0.f));
            }
    }
}

// == expert2: sigmoid(h1@W2+b2)*probs -> atomic scatter. grid (mb=16,c=16) ==
// wave: 1 m-frag x 64 cols (4 n-frags), K=512.
__global__ __launch_bounds__(64) void expert2_mfma_kernel(
        const short* __restrict__ h1bf, const short* __restrict__ W2t,
        const float* __restrict__ b2, const float* __restrict__ probs,
        const int* __restrict__ mapping, float* __restrict__ outexp) {
    const int l = threadIdx.x, lr = l & 15, g = l >> 4;
    const int mfb = blockIdx.x * 16, c = blockIdx.y;
    const short* ar = h1bf + ((size_t)c * B_ + mfb + lr) * 512;
    const short* wb = W2t + (size_t)c * (EPC * 512);

    f32x4 acc[4] = {};
    #pragma unroll 4
    for (int s = 0; s < 16; ++s) {
        const int k = s * 32 + g * 8;
        short8 a = *(const short8*)(ar + k);
        #pragma unroll
        for (int nf = 0; nf < 4; ++nf) {
            short8 bv = *(const short8*)(wb + (size_t)(nf * 16 + lr) * 512 + k);
            acc[nf] = __builtin_amdgcn_mfma_f32_16x16x32_bf16(a, bv, acc[nf], 0, 0, 0);
        }
    }
    #pragma unroll
    for (int nf = 0; nf < 4; ++nf) {
        const int e = nf * 16 + lr;
        const float bb = b2[c * EPC + e];
        const int tgt = mapping[c * EPC + e];
        #pragma unroll
        for (int r = 0; r < 4; ++r) {
            const int m = mfb + g * 4 + r;
            const float v = probs[m * NC + c] / (1.f + expf(-(acc[nf][r] + bb)));
            atomicAdd(&outexp[(size_t)m * NE + tgt], v);
        }
    }
}

// ===========================================================================
extern "C" void kernel_launch(void* const* d_in, const int* in_sizes, int n_in,
                              void* d_out, int out_size, void* d_ws, size_t ws_size,
                              hipStream_t stream) {
    const float* obs   = (const float*)d_in[0];
    const float* k1    = (const float*)d_in[1];
    const float* cb1   = (const float*)d_in[2];
    const float* k2    = (const float*)d_in[3];
    const float* cb2   = (const float*)d_in[4];
    const float* k3    = (const float*)d_in[5];
    const float* cb3   = (const float*)d_in[6];
    const float* Wproj = (const float*)d_in[7];
    const float* bproj = (const float*)d_in[8];
    const float* Wcat  = (const float*)d_in[9];
    const float* bcat  = (const float*)d_in[10];
    const float* W1    = (const float*)d_in[11];
    const float* b1    = (const float*)d_in[12];
    const float* W2    = (const float*)d_in[13];
    const float* b2    = (const float*)d_in[14];
    const int*   mapping = (const int*)d_in[15];

    float* out    = (float*)d_out;
    float* logits = out;                       // [256*16]
    float* outexp = out + B_ * NC;             // [256*512]
    float* hidden = out + B_ * NC + B_ * NE;   // [256*1024]

    // ws choreography (peak 21.70MB <= proven 22.70MB):
    // Region A [0,16.8M): x1bf@0 (6.55M) -> Wprojt@0 (6.42M, after conv2)
    //                     -> W1t@0 (16.78M, after proj) -> W2t@0 (after e1)
    //                     x2bf@6.55M (2.65M, dead after conv3)
    //                     featsbf@9.21M (1.61M, dead after proj)
    // Region B [16.8M,21.7M): hidbf, probs, k1bf, k2t, k3t, h1bf
    char* ws = (char*)d_ws;
    short* x1bf    = (short*)ws;
    short* Wprojt  = (short*)ws;
    short* W1t     = (short*)ws;
    short* W2t     = (short*)ws;
    short* x2bf    = (short*)(ws + 6553600);
    short* featsbf = (short*)(ws + 9207808);
    short* hidbf   = (short*)(ws + 16777216);
    float* probs   = (float*)(ws + 17301504);
    short* k1bf    = (short*)(ws + 17317888);
    short* k2t     = (short*)(ws + 17367040);
    short* k3t     = (short*)(ws + 17432576);
    short* h1bf    = (short*)(ws + 17506304);

    hipMemsetAsync(outexp, 0, (size_t)B_ * NE * sizeof(float), stream);

    prep_weights_kernel<<<dim3(368), 256, 0, stream>>>(k1, k2, k3, k1bf, k2t, k3t);
    conv1_mfma_kernel<<<dim3(4, B_), 448, 0, stream>>>(obs, k1bf, cb1, x1bf);
    conv2_mfma_kernel<<<dim3(1296), 64, 0, stream>>>(x1bf, k2t, cb2, x2bf);
    // Wprojt overwrites x1bf: must launch after conv2 (stream-ordered).
    transpose_cast_kernel<<<dim3(32, 98, 1), 256, 0, stream>>>(
        Wproj, Wprojt, FLAT, HID, 0, 0);
    conv3_mfma_kernel<<<dim3(784), 64, 0, stream>>>(x2bf, k3t, cb3, featsbf);
    proj_mfma_kernel<<<dim3(64, 8), 64, 0, stream>>>(featsbf, Wprojt, bproj, hidden, hidbf);
    cat_softmax_kernel<<<dim3(B_), 256, 0, stream>>>(hidden, Wcat, bcat, logits, probs);
    // W1t overwrites Wprojt/x2bf/featsbf: after proj.
    transpose_cast_kernel<<<dim3(16, 32, 16), 256, 0, stream>>>(
        W1, W1t, HID, 512, (long)HID * 512, (long)HID * 512);
    expert1_mfma_kernel<<<dim3(16, 4, 16), 64, 0, stream>>>(hidbf, W1t, b1, h1bf);
    // W2t overwrites W1t: after expert1.
    transpose_cast_kernel<<<dim3(2, 16, 16), 256, 0, stream>>>(
        W2, W2t, 512, EPC, (long)512 * EPC, (long)512 * EPC);
    expert2_mfma_kernel<<<dim3(16, 16), 64, 0, stream>>>(
        h1bf, W2t, b2, probs, mapping, outexp);
}